// Round 4
// baseline (649.975 us; speedup 1.0000x reference)
//
#include <hip/hip_runtime.h>
#include <hip/hip_bf16.h>
#include <math.h>

// EnhancedSparseMoE round 5: drop fp32->bf16 weight pre-conversion (ws is re-poisoned
// every iter -> cvt can't cache; 415 MB/iter wasted). MFMA kernels read fp32 weights
// directly, reg-staging B (fp32->bf16 pack -> swizzled ds_write). Revert to simple
// 2-sync m97-style loop (pipelining regressed twice), BK=64, keep XCD decode.
// T=2048 tokens, H=2048, I=1408, E=8, top-2.
#define T_TOK 2048
#define H_DIM 2048
#define I_DIM 1408
#define E_NUM 8
#define I2    2816   // 2*I

typedef __attribute__((ext_vector_type(8))) short short8;
typedef __attribute__((ext_vector_type(4))) float floatx4;
typedef __attribute__((ext_vector_type(8))) unsigned short bf16x8;
typedef __attribute__((ext_vector_type(4))) unsigned short bf16x4;
typedef unsigned short u16;

__device__ __forceinline__ u16 f2bf(float x) {   // RNE, matches __float2bfloat16
    unsigned u = __builtin_bit_cast(unsigned, x);
    return (u16)((u + 0x7FFFu + ((u >> 16) & 1u)) >> 16);
}

__device__ __forceinline__ bf16x8 pack8(float4 a, float4 b) {
    bf16x8 o;
    o[0] = f2bf(a.x); o[1] = f2bf(a.y); o[2] = f2bf(a.z); o[3] = f2bf(a.w);
    o[4] = f2bf(b.x); o[5] = f2bf(b.y); o[6] = f2bf(b.z); o[7] = f2bf(b.w);
    return o;
}

__device__ __forceinline__ floatx4 mfma16(short8 a, short8 b, floatx4 c) {
    return __builtin_amdgcn_mfma_f32_16x16x32_bf16(a, b, c, 0, 0, 0);
}

__device__ __forceinline__ void gload16(const u16* g, u16* l) {
    __builtin_amdgcn_global_load_lds(
        (const __attribute__((address_space(1))) unsigned int*)g,
        (__attribute__((address_space(3))) unsigned int*)l, 16, 0, 0);
}

// ---------------- gating (fp32 exact) + fused x->bf16 conversion ----------------
__global__ void moe_gating(const float* __restrict__ x, const float* __restrict__ gw,
                           u16* __restrict__ xb, float* __restrict__ wts,
                           int* __restrict__ counts, int* __restrict__ entries) {
    const int lane = threadIdx.x & 63;
    const int wv   = threadIdx.x >> 6;
    const int t    = blockIdx.x * 4 + wv;
    float acc[E_NUM];
#pragma unroll
    for (int e = 0; e < E_NUM; ++e) acc[e] = 0.f;
    const float4* xr = (const float4*)(x + (size_t)t * H_DIM);
    u16* xo = xb + (size_t)t * H_DIM;
#pragma unroll
    for (int j = 0; j < 8; ++j) {
        float4 xv = xr[lane + 64 * j];
        bf16x4 xw;
        xw[0] = f2bf(xv.x); xw[1] = f2bf(xv.y); xw[2] = f2bf(xv.z); xw[3] = f2bf(xv.w);
        *(bf16x4*)(xo + (lane + 64 * j) * 4) = xw;
#pragma unroll
        for (int e = 0; e < E_NUM; ++e) {
            float4 g = ((const float4*)(gw + (size_t)e * H_DIM))[lane + 64 * j];
            acc[e] += xv.x * g.x + xv.y * g.y + xv.z * g.z + xv.w * g.w;
        }
    }
#pragma unroll
    for (int off = 32; off > 0; off >>= 1)
#pragma unroll
        for (int e = 0; e < E_NUM; ++e) acc[e] += __shfl_xor(acc[e], off, 64);

    if (lane == 0) {
        int a = 0; float la = acc[0];
        for (int e = 1; e < E_NUM; ++e) if (acc[e] > la) { la = acc[e]; a = e; }
        int b = (a == 0) ? 1 : 0; float lb = acc[b];
        for (int e = 0; e < E_NUM; ++e)
            if (e != a && acc[e] > lb) { lb = acc[e]; b = e; }
        float wa = 1.f / (1.f + expf(lb - la));
        wts[t * 2 + 0] = wa;
        wts[t * 2 + 1] = 1.f - wa;
        int p0 = atomicAdd(&counts[a], 1); entries[a * T_TOK + p0] = t * 2;
        int p1 = atomicAdd(&counts[b], 1); entries[b * T_TOK + p1] = t * 2 + 1;
    }
}

// ---------------- gemm1: act[v] = silu(x.Wg^T) * (x.Wu^T), bf16 MFMA ----------------
// Tile M=128 x N=64 (G and U), BK=64; 4 waves each 64x32 per matrix.
// 1-D grid 2816 = 8e * 22tn * 16tm; e=bid&7 pins expert->XCD, tm fastest so the
// ~4 working tm-blocks sharing a weight tile are dispatch-adjacent (L2 dedup).
// A (bf16 tokens) via global_load_lds; B (fp32 weights) reg-staged with cvt.
// LDS rows = 64 bf16 = 128 B = 8 chunks of 16 B; phys chunk = logical ^ (row&7).
__global__ __launch_bounds__(256)
void moe_mfma1(const u16* __restrict__ xb, const float* __restrict__ w1,
               const int* __restrict__ counts, const int* __restrict__ entries,
               u16* __restrict__ act) {
    const int bid = blockIdx.x;
    const int e   = bid & 7;
    const int rem = bid >> 3;          // 0..351
    const int tn  = rem >> 4;          // 0..21, o-base = tn*64
    const int tm  = rem & 15;          // 0..15
    const int ne  = counts[e];
    if (tm * 128 >= ne) return;

    __shared__ __align__(16) u16 As[128 * 64];
    __shared__ __align__(16) u16 Bg[64 * 64];
    __shared__ __align__(16) u16 Bu[64 * 64];
    __shared__ int rowv[128];

    const int tid = threadIdx.x;
    if (tid < 128) {
        int r = tm * 128 + tid;
        rowv[tid] = (r < ne) ? entries[(size_t)e * T_TOK + r] : -1;
    }
    __syncthreads();

    // A staging: 4 rounds x 256 thr x 16B = 16 KB (128 rows x 64 k).
    // gload_lds dest is linear (i*16B); swizzle applied to the global source chunk.
    const u16* asrc[4]; int ad[4];
#pragma unroll
    for (int q = 0; q < 4; ++q) {
        int i = q * 256 + tid;
        int row = i >> 3, pc = i & 7;
        int lc = pc ^ (row & 7);
        int v = rowv[row];
        int tok = (v < 0) ? 0 : (v >> 1);
        asrc[q] = xb + (size_t)tok * H_DIM + lc * 8;
        ad[q] = i * 8;
    }
    // B staging (fp32): thread owns row tid>>2, 16 cols at (tid&3)*16, for G and U.
    const int brow = tid >> 2;
    const int bc16 = (tid & 3) * 16;
    const float* gsrc = w1 + ((size_t)e * I2 + tn * 64 + brow) * H_DIM + bc16;
    const float* usrc = gsrc + (size_t)I_DIM * H_DIM;
    const int lc0 = (tid & 3) * 2;
    u16* bgd0 = Bg + brow * 64 + ((lc0    ) ^ (brow & 7)) * 8;
    u16* bgd1 = Bg + brow * 64 + ((lc0 + 1) ^ (brow & 7)) * 8;
    u16* bud0 = Bu + brow * 64 + ((lc0    ) ^ (brow & 7)) * 8;
    u16* bud1 = Bu + brow * 64 + ((lc0 + 1) ^ (brow & 7)) * 8;

    const int lane = tid & 63, wid = tid >> 6;
    const int wm = wid & 1, wn = wid >> 1;

    floatx4 accG[4][2], accU[4][2];
    const floatx4 z4 = {0.f, 0.f, 0.f, 0.f};
#pragma unroll
    for (int mi = 0; mi < 4; ++mi)
#pragma unroll
        for (int ni = 0; ni < 2; ++ni) { accG[mi][ni] = z4; accU[mi][ni] = z4; }

    int aoff[4][2], boff[2][2];
#pragma unroll
    for (int mi = 0; mi < 4; ++mi) {
        int m = wm * 64 + mi * 16 + (lane & 15);
#pragma unroll
        for (int kk = 0; kk < 2; ++kk)
            aoff[mi][kk] = m * 64 + (((kk * 4 + (lane >> 4)) ^ (m & 7)) * 8);
    }
#pragma unroll
    for (int ni = 0; ni < 2; ++ni) {
        int n = wn * 32 + ni * 16 + (lane & 15);
#pragma unroll
        for (int kk = 0; kk < 2; ++kk)
            boff[ni][kk] = n * 64 + (((kk * 4 + (lane >> 4)) ^ (n & 7)) * 8);
    }

#pragma unroll 1
    for (int k0 = 0; k0 < H_DIM; k0 += 64) {
#pragma unroll
        for (int q = 0; q < 4; ++q) gload16(asrc[q] + k0, As + ad[q]);
        {
            const float4* g4 = (const float4*)(gsrc + k0);
            const float4* u4 = (const float4*)(usrc + k0);
            float4 a0 = g4[0], a1 = g4[1], a2 = g4[2], a3 = g4[3];
            float4 b0 = u4[0], b1 = u4[1], b2 = u4[2], b3 = u4[3];
            *(bf16x8*)bgd0 = pack8(a0, a1);
            *(bf16x8*)bgd1 = pack8(a2, a3);
            *(bf16x8*)bud0 = pack8(b0, b1);
            *(bf16x8*)bud1 = pack8(b2, b3);
        }
        __syncthreads();
#pragma unroll
        for (int kk = 0; kk < 2; ++kk) {
            short8 a[4], g2[2], u2[2];
#pragma unroll
            for (int mi = 0; mi < 4; ++mi) a[mi] = *(const short8*)(As + aoff[mi][kk]);
#pragma unroll
            for (int ni = 0; ni < 2; ++ni) {
                g2[ni] = *(const short8*)(Bg + boff[ni][kk]);
                u2[ni] = *(const short8*)(Bu + boff[ni][kk]);
            }
#pragma unroll
            for (int mi = 0; mi < 4; ++mi)
#pragma unroll
                for (int ni = 0; ni < 2; ++ni) {
                    accG[mi][ni] = mfma16(a[mi], g2[ni], accG[mi][ni]);
                    accU[mi][ni] = mfma16(a[mi], u2[ni], accU[mi][ni]);
                }
        }
        __syncthreads();
    }

    const int obase = tn * 64 + wn * 32;
#pragma unroll
    for (int mi = 0; mi < 4; ++mi)
#pragma unroll
        for (int ni = 0; ni < 2; ++ni)
#pragma unroll
            for (int r = 0; r < 4; ++r) {
                int row = wm * 64 + mi * 16 + (lane >> 4) * 4 + r;
                int v = rowv[row];
                if (v < 0) continue;
                float g = accG[mi][ni][r], u = accU[mi][ni][r];
                float s = g / (1.f + expf(-g)) * u;
                act[(size_t)v * I_DIM + obase + ni * 16 + (lane & 15)] = f2bf(s);
            }
}

// ---------------- gemm2: out[t] += wts[v] * act[v].W2^T, bf16 MFMA ----------------
// Tile M=128 x N=128, BK=64; 4 waves each 64x64. 1-D grid 2048 = 8e*16tn*16tm.
// A (bf16 act) via global_load_lds; B (fp32 w2) reg-staged with cvt.
__global__ __launch_bounds__(256)
void moe_mfma2(const u16* __restrict__ act, const float* __restrict__ w2,
               const int* __restrict__ counts, const int* __restrict__ entries,
               const float* __restrict__ wts, float* __restrict__ out) {
    const int bid = blockIdx.x;
    const int e   = bid & 7;
    const int rem = bid >> 3;          // 0..255
    const int tn  = rem >> 4;          // 0..15, h-base = tn*128
    const int tm  = rem & 15;          // 0..15
    const int ne  = counts[e];
    if (tm * 128 >= ne) return;

    __shared__ __align__(16) u16 As[128 * 64];
    __shared__ __align__(16) u16 Bs[128 * 64];
    __shared__ int   rowv[128];
    __shared__ int   rowt[128];
    __shared__ float roww[128];

    const int tid = threadIdx.x;
    if (tid < 128) {
        int r = tm * 128 + tid;
        int v = (r < ne) ? entries[(size_t)e * T_TOK + r] : -1;
        rowv[tid] = v;
        rowt[tid] = (v < 0) ? 0 : (v >> 1);
        roww[tid] = (v < 0) ? 0.f : wts[v];
    }
    __syncthreads();

    // A staging: 4 rounds (128 rows x 64 k bf16), swizzled source.
    const u16* asrc[4]; int ad[4];
#pragma unroll
    for (int q = 0; q < 4; ++q) {
        int i = q * 256 + tid;
        int row = i >> 3, pc = i & 7;
        int lc = pc ^ (row & 7);
        int v = rowv[row]; if (v < 0) v = 0;
        asrc[q] = act + (size_t)v * I_DIM + lc * 8;
        ad[q] = i * 8;
    }
    // B staging (fp32 w2): thread owns row tid>>1, 32 cols at (tid&1)*32.
    const int brow = tid >> 1;
    const int bc32 = (tid & 1) * 32;
    const float* bsrc = w2 + ((size_t)e * H_DIM + tn * 128 + brow) * I_DIM + bc32;
    const int lcb = (tid & 1) * 4;
    u16* bd[4];
#pragma unroll
    for (int j = 0; j < 4; ++j)
        bd[j] = Bs + brow * 64 + (((lcb + j) ^ (brow & 7)) * 8);

    const int lane = tid & 63, wid = tid >> 6;
    const int wm = wid & 1, wn = wid >> 1;

    floatx4 acc[4][4];
    const floatx4 z4 = {0.f, 0.f, 0.f, 0.f};
#pragma unroll
    for (int mi = 0; mi < 4; ++mi)
#pragma unroll
        for (int ni = 0; ni < 4; ++ni) acc[mi][ni] = z4;

    int aoff[4][2], boff[4][2];
#pragma unroll
    for (int mi = 0; mi < 4; ++mi) {
        int m = wm * 64 + mi * 16 + (lane & 15);
#pragma unroll
        for (int kk = 0; kk < 2; ++kk)
            aoff[mi][kk] = m * 64 + (((kk * 4 + (lane >> 4)) ^ (m & 7)) * 8);
    }
#pragma unroll
    for (int ni = 0; ni < 4; ++ni) {
        int n = wn * 64 + ni * 16 + (lane & 15);
#pragma unroll
        for (int kk = 0; kk < 2; ++kk)
            boff[ni][kk] = n * 64 + (((kk * 4 + (lane >> 4)) ^ (n & 7)) * 8);
    }

#pragma unroll 1
    for (int k0 = 0; k0 < I_DIM; k0 += 64) {
#pragma unroll
        for (int q = 0; q < 4; ++q) gload16(asrc[q] + k0, As + ad[q]);
        {
            const float4* b4 = (const float4*)(bsrc + k0);
            float4 t0 = b4[0], t1 = b4[1], t2 = b4[2], t3 = b4[3];
            float4 t4 = b4[4], t5 = b4[5], t6 = b4[6], t7 = b4[7];
            *(bf16x8*)bd[0] = pack8(t0, t1);
            *(bf16x8*)bd[1] = pack8(t2, t3);
            *(bf16x8*)bd[2] = pack8(t4, t5);
            *(bf16x8*)bd[3] = pack8(t6, t7);
        }
        __syncthreads();
#pragma unroll
        for (int kk = 0; kk < 2; ++kk) {
            short8 a[4], b[4];
#pragma unroll
            for (int mi = 0; mi < 4; ++mi) a[mi] = *(const short8*)(As + aoff[mi][kk]);
#pragma unroll
            for (int ni = 0; ni < 4; ++ni) b[ni] = *(const short8*)(Bs + boff[ni][kk]);
#pragma unroll
            for (int mi = 0; mi < 4; ++mi)
#pragma unroll
                for (int ni = 0; ni < 4; ++ni)
                    acc[mi][ni] = mfma16(a[mi], b[ni], acc[mi][ni]);
        }
        __syncthreads();
    }

    const int hbase = tn * 128 + wn * 64;
#pragma unroll
    for (int mi = 0; mi < 4; ++mi)
#pragma unroll
        for (int ni = 0; ni < 4; ++ni)
#pragma unroll
            for (int r = 0; r < 4; ++r) {
                int row = wm * 64 + mi * 16 + (lane >> 4) * 4 + r;
                if (rowv[row] < 0) continue;
                atomicAdd(out + (size_t)rowt[row] * H_DIM + hbase + ni * 16 + (lane & 15),
                          roww[row] * acc[mi][ni][r]);
            }
}

extern "C" void kernel_launch(void* const* d_in, const int* in_sizes, int n_in,
                              void* d_out, int out_size, void* d_ws, size_t ws_size,
                              hipStream_t stream) {
    const float* x  = (const float*)d_in[0];   // [T, H]
    const float* gw = (const float*)d_in[1];   // [E, H]
    const float* w1 = (const float*)d_in[2];   // [E, 2I, H]
    const float* w2 = (const float*)d_in[3];   // [E, H, I]
    float* out = (float*)d_out;                // [T, H]

    char* ws = (char*)d_ws;
    int*   counts  = (int*)ws;                               // 256 B
    int*   entries = (int*)(ws + 256);                       // 64 KB
    float* wts     = (float*)(ws + 256 + 65536);             // 16 KB
    u16* xb  = (u16*)(ws + 131072);                  // 8 MB  (bf16 tokens)
    u16* act = xb + (size_t)T_TOK * H_DIM;           // 11.5 MB (bf16 activations)

    (void)hipMemsetAsync(counts, 0, 256, stream);
    (void)hipMemsetAsync(out, 0, (size_t)T_TOK * H_DIM * sizeof(float), stream);

    moe_gating<<<T_TOK / 4, 256, 0, stream>>>(x, gw, xb, wts, counts, entries);
    moe_mfma1<<<dim3(22 * 16 * E_NUM), 256, 0, stream>>>(xb, w1, counts, entries, act);
    moe_mfma2<<<dim3(16 * 16 * E_NUM), 256, 0, stream>>>(act, w2, counts, entries, wts, out);
}

// Round 5
// 567.952 us; speedup vs baseline: 1.1444x; 1.1444x over previous
//
#include <hip/hip_runtime.h>
#include <hip/hip_bf16.h>
#include <math.h>

// EnhancedSparseMoE round 6: R0 base (bf16 pre-converted weights via global_load_lds,
// simple 2-sync loop) + BK=64 conflict-free xor8 swizzle (R4-verified, 6.7M->0) +
// XCD co-location decode (R3-verified 3.4x fetch cut) + atomic-free gemm2 epilogue
// (slot buffer aliased into w1b space + combine kernel; bitwise-identical numerics).
// T=2048 tokens, H=2048, I=1408, E=8, top-2.
#define T_TOK 2048
#define H_DIM 2048
#define I_DIM 1408
#define E_NUM 8
#define I2    2816   // 2*I

typedef __attribute__((ext_vector_type(8))) short short8;
typedef __attribute__((ext_vector_type(4))) float floatx4;
typedef __attribute__((ext_vector_type(8))) unsigned short bf16x8;
typedef __attribute__((ext_vector_type(4))) unsigned short bf16x4;
typedef unsigned short u16;

__device__ __forceinline__ u16 f2bf(float x) {   // RNE, matches __float2bfloat16
    unsigned u = __builtin_bit_cast(unsigned, x);
    return (u16)((u + 0x7FFFu + ((u >> 16) & 1u)) >> 16);
}

__device__ __forceinline__ bf16x8 pack8(float4 a, float4 b) {
    bf16x8 o;
    o[0] = f2bf(a.x); o[1] = f2bf(a.y); o[2] = f2bf(a.z); o[3] = f2bf(a.w);
    o[4] = f2bf(b.x); o[5] = f2bf(b.y); o[6] = f2bf(b.z); o[7] = f2bf(b.w);
    return o;
}

__device__ __forceinline__ floatx4 mfma16(short8 a, short8 b, floatx4 c) {
    return __builtin_amdgcn_mfma_f32_16x16x32_bf16(a, b, c, 0, 0, 0);
}

__device__ __forceinline__ void gload16(const u16* g, u16* l) {
    __builtin_amdgcn_global_load_lds(
        (const __attribute__((address_space(1))) unsigned int*)g,
        (__attribute__((address_space(3))) unsigned int*)l, 16, 0, 0);
}

// ---------------- gating (fp32 exact) + fused x->bf16 conversion ----------------
__global__ void moe_gating(const float* __restrict__ x, const float* __restrict__ gw,
                           u16* __restrict__ xb, float* __restrict__ wts,
                           int* __restrict__ counts, int* __restrict__ entries) {
    const int lane = threadIdx.x & 63;
    const int wv   = threadIdx.x >> 6;
    const int t    = blockIdx.x * 4 + wv;
    float acc[E_NUM];
#pragma unroll
    for (int e = 0; e < E_NUM; ++e) acc[e] = 0.f;
    const float4* xr = (const float4*)(x + (size_t)t * H_DIM);
    u16* xo = xb + (size_t)t * H_DIM;
#pragma unroll
    for (int j = 0; j < 8; ++j) {
        float4 xv = xr[lane + 64 * j];
        bf16x4 xw;
        xw[0] = f2bf(xv.x); xw[1] = f2bf(xv.y); xw[2] = f2bf(xv.z); xw[3] = f2bf(xv.w);
        *(bf16x4*)(xo + (lane + 64 * j) * 4) = xw;
#pragma unroll
        for (int e = 0; e < E_NUM; ++e) {
            float4 g = ((const float4*)(gw + (size_t)e * H_DIM))[lane + 64 * j];
            acc[e] += xv.x * g.x + xv.y * g.y + xv.z * g.z + xv.w * g.w;
        }
    }
#pragma unroll
    for (int off = 32; off > 0; off >>= 1)
#pragma unroll
        for (int e = 0; e < E_NUM; ++e) acc[e] += __shfl_xor(acc[e], off, 64);

    if (lane == 0) {
        int a = 0; float la = acc[0];
        for (int e = 1; e < E_NUM; ++e) if (acc[e] > la) { la = acc[e]; a = e; }
        int b = (a == 0) ? 1 : 0; float lb = acc[b];
        for (int e = 0; e < E_NUM; ++e)
            if (e != a && acc[e] > lb) { lb = acc[e]; b = e; }
        float wa = 1.f / (1.f + expf(lb - la));
        wts[t * 2 + 0] = wa;
        wts[t * 2 + 1] = 1.f - wa;
        int p0 = atomicAdd(&counts[a], 1); entries[a * T_TOK + p0] = t * 2;
        int p1 = atomicAdd(&counts[b], 1); entries[b * T_TOK + p1] = t * 2 + 1;
    }
}

// ---------------- fp32 -> bf16 weight conversion (unconditional; ws is re-poisoned) ----
__global__ __launch_bounds__(256)
void cvt_bf16(const float* __restrict__ src, u16* __restrict__ dst, long n8) {
    const float4* s4 = (const float4*)src;
    const long stride = (long)gridDim.x * 256;
    for (long i = (long)blockIdx.x * 256 + threadIdx.x; i < n8; i += stride) {
        float4 a = s4[2 * i], b = s4[2 * i + 1];
        *(bf16x8*)(dst + (size_t)i * 8) = pack8(a, b);
    }
}

// ---------------- gemm1 (pre): act[v] = silu(x.Wg^T) * (x.Wu^T) ----------------
// Tile M=128 x N=64 (G and U), BK=64; 4 waves each 64x32 per matrix.
// 1-D grid 2816 = 8e * 22tn * 16tm; e=bid&7 pins expert->XCD; tm fastest.
// A and B both bf16 via global_load_lds; swizzle on SOURCE chunk (lc = pc^(row&7)),
// LDS dest linear, read-side XOR recovers -> 0 bank conflicts (R4-verified).
__global__ __launch_bounds__(256)
void moe_mfma1_pre(const u16* __restrict__ xb, const u16* __restrict__ w1b,
                   const int* __restrict__ counts, const int* __restrict__ entries,
                   u16* __restrict__ act) {
    const int bid = blockIdx.x;
    const int e   = bid & 7;
    const int rem = bid >> 3;          // 0..351
    const int tn  = rem >> 4;          // 0..21, o-base = tn*64
    const int tm  = rem & 15;          // 0..15
    const int ne  = counts[e];
    if (tm * 128 >= ne) return;

    __shared__ __align__(16) u16 As[128 * 64];
    __shared__ __align__(16) u16 Bg[64 * 64];
    __shared__ __align__(16) u16 Bu[64 * 64];
    __shared__ int rowv[128];

    const int tid = threadIdx.x;
    if (tid < 128) {
        int r = tm * 128 + tid;
        rowv[tid] = (r < ne) ? entries[(size_t)e * T_TOK + r] : -1;
    }
    __syncthreads();

    // A staging: 4 rounds x 256 thr x 16B (128 rows x 64 k)
    const u16* asrc[4]; int ad[4];
#pragma unroll
    for (int q = 0; q < 4; ++q) {
        int i = q * 256 + tid;
        int row = i >> 3, pc = i & 7;
        int lc = pc ^ (row & 7);
        int v = rowv[row];
        int tok = (v < 0) ? 0 : (v >> 1);
        asrc[q] = xb + (size_t)tok * H_DIM + lc * 8;
        ad[q] = i * 8;
    }
    // B staging: 2 rounds each for G and U (64 rows x 64 k)
    const u16* gsrc[2]; const u16* usrc[2]; int bd2[2];
#pragma unroll
    for (int q = 0; q < 2; ++q) {
        int i = q * 256 + tid;
        int row = i >> 3, pc = i & 7;
        int lc = pc ^ (row & 7);
        size_t off = ((size_t)e * I2 + tn * 64 + row) * H_DIM + lc * 8;
        gsrc[q] = w1b + off;
        usrc[q] = w1b + off + (size_t)I_DIM * H_DIM;
        bd2[q] = i * 8;
    }

    const int lane = tid & 63, wid = tid >> 6;
    const int wm = wid & 1, wn = wid >> 1;

    floatx4 accG[4][2], accU[4][2];
    const floatx4 z4 = {0.f, 0.f, 0.f, 0.f};
#pragma unroll
    for (int mi = 0; mi < 4; ++mi)
#pragma unroll
        for (int ni = 0; ni < 2; ++ni) { accG[mi][ni] = z4; accU[mi][ni] = z4; }

    int aoff[4][2], boff[2][2];
#pragma unroll
    for (int mi = 0; mi < 4; ++mi) {
        int m = wm * 64 + mi * 16 + (lane & 15);
#pragma unroll
        for (int kk = 0; kk < 2; ++kk)
            aoff[mi][kk] = m * 64 + (((kk * 4 + (lane >> 4)) ^ (m & 7)) * 8);
    }
#pragma unroll
    for (int ni = 0; ni < 2; ++ni) {
        int n = wn * 32 + ni * 16 + (lane & 15);
#pragma unroll
        for (int kk = 0; kk < 2; ++kk)
            boff[ni][kk] = n * 64 + (((kk * 4 + (lane >> 4)) ^ (n & 7)) * 8);
    }

#pragma unroll 1
    for (int k0 = 0; k0 < H_DIM; k0 += 64) {
#pragma unroll
        for (int q = 0; q < 4; ++q) gload16(asrc[q] + k0, As + ad[q]);
#pragma unroll
        for (int q = 0; q < 2; ++q) {
            gload16(gsrc[q] + k0, Bg + bd2[q]);
            gload16(usrc[q] + k0, Bu + bd2[q]);
        }
        __syncthreads();
#pragma unroll
        for (int kk = 0; kk < 2; ++kk) {
            short8 a[4], g2[2], u2[2];
#pragma unroll
            for (int mi = 0; mi < 4; ++mi) a[mi] = *(const short8*)(As + aoff[mi][kk]);
#pragma unroll
            for (int ni = 0; ni < 2; ++ni) {
                g2[ni] = *(const short8*)(Bg + boff[ni][kk]);
                u2[ni] = *(const short8*)(Bu + boff[ni][kk]);
            }
#pragma unroll
            for (int mi = 0; mi < 4; ++mi)
#pragma unroll
                for (int ni = 0; ni < 2; ++ni) {
                    accG[mi][ni] = mfma16(a[mi], g2[ni], accG[mi][ni]);
                    accU[mi][ni] = mfma16(a[mi], u2[ni], accU[mi][ni]);
                }
        }
        __syncthreads();
    }

    const int obase = tn * 64 + wn * 32;
#pragma unroll
    for (int mi = 0; mi < 4; ++mi)
#pragma unroll
        for (int ni = 0; ni < 2; ++ni)
#pragma unroll
            for (int r = 0; r < 4; ++r) {
                int row = wm * 64 + mi * 16 + (lane >> 4) * 4 + r;
                int v = rowv[row];
                if (v < 0) continue;
                float g = accG[mi][ni][r], u = accU[mi][ni][r];
                float s = g / (1.f + expf(-g)) * u;
                act[(size_t)v * I_DIM + obase + ni * 16 + (lane & 15)] = f2bf(s);
            }
}

// ---------------- gemm2 (pre): slot[v] = wts[v] * act[v].W2^T  (no atomics) --------
// Tile M=128 x N=128, BK=64; 4 waves each 64x64. 1-D grid 2048 = 8e*16tn*16tm.
__global__ __launch_bounds__(256)
void moe_mfma2_pre(const u16* __restrict__ act, const u16* __restrict__ w2b,
                   const int* __restrict__ counts, const int* __restrict__ entries,
                   const float* __restrict__ wts, float* __restrict__ slot) {
    const int bid = blockIdx.x;
    const int e   = bid & 7;
    const int rem = bid >> 3;          // 0..255
    const int tn  = rem >> 4;          // 0..15, h-base = tn*128
    const int tm  = rem & 15;          // 0..15
    const int ne  = counts[e];
    if (tm * 128 >= ne) return;

    __shared__ __align__(16) u16 As[128 * 64];
    __shared__ __align__(16) u16 Bs[128 * 64];
    __shared__ int   rowv[128];
    __shared__ float roww[128];

    const int tid = threadIdx.x;
    if (tid < 128) {
        int r = tm * 128 + tid;
        int v = (r < ne) ? entries[(size_t)e * T_TOK + r] : -1;
        rowv[tid] = v;
        roww[tid] = (v < 0) ? 0.f : wts[v];
    }
    __syncthreads();

    const u16* asrc[4]; const u16* bsrc[4]; int ad[4];
#pragma unroll
    for (int q = 0; q < 4; ++q) {
        int i = q * 256 + tid;
        int row = i >> 3, pc = i & 7;
        int lc = pc ^ (row & 7);
        int v = rowv[row]; if (v < 0) v = 0;
        asrc[q] = act + (size_t)v * I_DIM + lc * 8;
        bsrc[q] = w2b + ((size_t)e * H_DIM + tn * 128 + row) * I_DIM + lc * 8;
        ad[q] = i * 8;
    }

    const int lane = tid & 63, wid = tid >> 6;
    const int wm = wid & 1, wn = wid >> 1;

    floatx4 acc[4][4];
    const floatx4 z4 = {0.f, 0.f, 0.f, 0.f};
#pragma unroll
    for (int mi = 0; mi < 4; ++mi)
#pragma unroll
        for (int ni = 0; ni < 4; ++ni) acc[mi][ni] = z4;

    int aoff[4][2], boff[4][2];
#pragma unroll
    for (int mi = 0; mi < 4; ++mi) {
        int m = wm * 64 + mi * 16 + (lane & 15);
#pragma unroll
        for (int kk = 0; kk < 2; ++kk)
            aoff[mi][kk] = m * 64 + (((kk * 4 + (lane >> 4)) ^ (m & 7)) * 8);
    }
#pragma unroll
    for (int ni = 0; ni < 4; ++ni) {
        int n = wn * 64 + ni * 16 + (lane & 15);
#pragma unroll
        for (int kk = 0; kk < 2; ++kk)
            boff[ni][kk] = n * 64 + (((kk * 4 + (lane >> 4)) ^ (n & 7)) * 8);
    }

#pragma unroll 1
    for (int k0 = 0; k0 < I_DIM; k0 += 64) {
#pragma unroll
        for (int q = 0; q < 4; ++q) {
            gload16(asrc[q] + k0, As + ad[q]);
            gload16(bsrc[q] + k0, Bs + ad[q]);
        }
        __syncthreads();
#pragma unroll
        for (int kk = 0; kk < 2; ++kk) {
            short8 a[4], b[4];
#pragma unroll
            for (int mi = 0; mi < 4; ++mi) a[mi] = *(const short8*)(As + aoff[mi][kk]);
#pragma unroll
            for (int ni = 0; ni < 4; ++ni) b[ni] = *(const short8*)(Bs + boff[ni][kk]);
#pragma unroll
            for (int mi = 0; mi < 4; ++mi)
#pragma unroll
                for (int ni = 0; ni < 4; ++ni)
                    acc[mi][ni] = mfma16(a[mi], b[ni], acc[mi][ni]);
        }
        __syncthreads();
    }

    const int hbase = tn * 128 + wn * 64;
#pragma unroll
    for (int mi = 0; mi < 4; ++mi)
#pragma unroll
        for (int ni = 0; ni < 4; ++ni)
#pragma unroll
            for (int r = 0; r < 4; ++r) {
                int row = wm * 64 + mi * 16 + (lane >> 4) * 4 + r;
                int v = rowv[row];
                if (v < 0) continue;
                slot[(size_t)v * H_DIM + hbase + ni * 16 + (lane & 15)] =
                    roww[row] * acc[mi][ni][r];
            }
}

// ---------------- combine: out[t] = slot[2t] + slot[2t+1] ----------------
__global__ __launch_bounds__(256)
void moe_combine(const float* __restrict__ slot, float* __restrict__ out) {
    int i = blockIdx.x * 256 + threadIdx.x;       // over T*H/4 float4s
    int t = i >> 9, c = i & 511;                  // H/4 = 512
    const float4* s4 = (const float4*)slot;
    float4 a = s4[(size_t)(2 * t) * 512 + c];
    float4 b = s4[(size_t)(2 * t + 1) * 512 + c];
    float4 o; o.x = a.x + b.x; o.y = a.y + b.y; o.z = a.z + b.z; o.w = a.w + b.w;
    ((float4*)out)[i] = o;
}

// ---------------- fallback kernels (ws too small): fp32 weights direct, atomics ----
__global__ __launch_bounds__(256)
void moe_mfma1_f32(const u16* __restrict__ xb, const float* __restrict__ w1,
                   const int* __restrict__ counts, const int* __restrict__ entries,
                   u16* __restrict__ act) {
    const int bid = blockIdx.x;
    const int e   = bid & 7;
    const int rem = bid >> 3;
    const int tn  = rem >> 4;
    const int tm  = rem & 15;
    const int ne  = counts[e];
    if (tm * 128 >= ne) return;

    __shared__ __align__(16) u16 As[128 * 64];
    __shared__ __align__(16) u16 Bg[64 * 64];
    __shared__ __align__(16) u16 Bu[64 * 64];
    __shared__ int rowv[128];

    const int tid = threadIdx.x;
    if (tid < 128) {
        int r = tm * 128 + tid;
        rowv[tid] = (r < ne) ? entries[(size_t)e * T_TOK + r] : -1;
    }
    __syncthreads();

    const u16* asrc[4]; int ad[4];
#pragma unroll
    for (int q = 0; q < 4; ++q) {
        int i = q * 256 + tid;
        int row = i >> 3, pc = i & 7;
        int lc = pc ^ (row & 7);
        int v = rowv[row];
        int tok = (v < 0) ? 0 : (v >> 1);
        asrc[q] = xb + (size_t)tok * H_DIM + lc * 8;
        ad[q] = i * 8;
    }
    const int brow = tid >> 2;
    const int bc16 = (tid & 3) * 16;
    const float* gsrc = w1 + ((size_t)e * I2 + tn * 64 + brow) * H_DIM + bc16;
    const float* usrc = gsrc + (size_t)I_DIM * H_DIM;
    const int lc0 = (tid & 3) * 2;
    u16* bgd0 = Bg + brow * 64 + ((lc0    ) ^ (brow & 7)) * 8;
    u16* bgd1 = Bg + brow * 64 + ((lc0 + 1) ^ (brow & 7)) * 8;
    u16* bud0 = Bu + brow * 64 + ((lc0    ) ^ (brow & 7)) * 8;
    u16* bud1 = Bu + brow * 64 + ((lc0 + 1) ^ (brow & 7)) * 8;

    const int lane = tid & 63, wid = tid >> 6;
    const int wm = wid & 1, wn = wid >> 1;

    floatx4 accG[4][2], accU[4][2];
    const floatx4 z4 = {0.f, 0.f, 0.f, 0.f};
#pragma unroll
    for (int mi = 0; mi < 4; ++mi)
#pragma unroll
        for (int ni = 0; ni < 2; ++ni) { accG[mi][ni] = z4; accU[mi][ni] = z4; }

    int aoff[4][2], boff[2][2];
#pragma unroll
    for (int mi = 0; mi < 4; ++mi) {
        int m = wm * 64 + mi * 16 + (lane & 15);
#pragma unroll
        for (int kk = 0; kk < 2; ++kk)
            aoff[mi][kk] = m * 64 + (((kk * 4 + (lane >> 4)) ^ (m & 7)) * 8);
    }
#pragma unroll
    for (int ni = 0; ni < 2; ++ni) {
        int n = wn * 32 + ni * 16 + (lane & 15);
#pragma unroll
        for (int kk = 0; kk < 2; ++kk)
            boff[ni][kk] = n * 64 + (((kk * 4 + (lane >> 4)) ^ (n & 7)) * 8);
    }

#pragma unroll 1
    for (int k0 = 0; k0 < H_DIM; k0 += 64) {
#pragma unroll
        for (int q = 0; q < 4; ++q) gload16(asrc[q] + k0, As + ad[q]);
        {
            const float4* g4 = (const float4*)(gsrc + k0);
            const float4* u4 = (const float4*)(usrc + k0);
            float4 a0 = g4[0], a1 = g4[1], a2 = g4[2], a3 = g4[3];
            float4 b0 = u4[0], b1 = u4[1], b2 = u4[2], b3 = u4[3];
            *(bf16x8*)bgd0 = pack8(a0, a1);
            *(bf16x8*)bgd1 = pack8(a2, a3);
            *(bf16x8*)bud0 = pack8(b0, b1);
            *(bf16x8*)bud1 = pack8(b2, b3);
        }
        __syncthreads();
#pragma unroll
        for (int kk = 0; kk < 2; ++kk) {
            short8 a[4], g2[2], u2[2];
#pragma unroll
            for (int mi = 0; mi < 4; ++mi) a[mi] = *(const short8*)(As + aoff[mi][kk]);
#pragma unroll
            for (int ni = 0; ni < 2; ++ni) {
                g2[ni] = *(const short8*)(Bg + boff[ni][kk]);
                u2[ni] = *(const short8*)(Bu + boff[ni][kk]);
            }
#pragma unroll
            for (int mi = 0; mi < 4; ++mi)
#pragma unroll
                for (int ni = 0; ni < 2; ++ni) {
                    accG[mi][ni] = mfma16(a[mi], g2[ni], accG[mi][ni]);
                    accU[mi][ni] = mfma16(a[mi], u2[ni], accU[mi][ni]);
                }
        }
        __syncthreads();
    }

    const int obase = tn * 64 + wn * 32;
#pragma unroll
    for (int mi = 0; mi < 4; ++mi)
#pragma unroll
        for (int ni = 0; ni < 2; ++ni)
#pragma unroll
            for (int r = 0; r < 4; ++r) {
                int row = wm * 64 + mi * 16 + (lane >> 4) * 4 + r;
                int v = rowv[row];
                if (v < 0) continue;
                float g = accG[mi][ni][r], u = accU[mi][ni][r];
                float s = g / (1.f + expf(-g)) * u;
                act[(size_t)v * I_DIM + obase + ni * 16 + (lane & 15)] = f2bf(s);
            }
}

__global__ __launch_bounds__(256)
void moe_mfma2_f32(const u16* __restrict__ act, const float* __restrict__ w2,
                   const int* __restrict__ counts, const int* __restrict__ entries,
                   const float* __restrict__ wts, float* __restrict__ out) {
    const int bid = blockIdx.x;
    const int e   = bid & 7;
    const int rem = bid >> 3;
    const int tn  = rem >> 4;
    const int tm  = rem & 15;
    const int ne  = counts[e];
    if (tm * 128 >= ne) return;

    __shared__ __align__(16) u16 As[128 * 64];
    __shared__ __align__(16) u16 Bs[128 * 64];
    __shared__ int   rowv[128];
    __shared__ int   rowt[128];
    __shared__ float roww[128];

    const int tid = threadIdx.x;
    if (tid < 128) {
        int r = tm * 128 + tid;
        int v = (r < ne) ? entries[(size_t)e * T_TOK + r] : -1;
        rowv[tid] = v;
        rowt[tid] = (v < 0) ? 0 : (v >> 1);
        roww[tid] = (v < 0) ? 0.f : wts[v];
    }
    __syncthreads();

    const u16* asrc[4]; int ad[4];
#pragma unroll
    for (int q = 0; q < 4; ++q) {
        int i = q * 256 + tid;
        int row = i >> 3, pc = i & 7;
        int lc = pc ^ (row & 7);
        int v = rowv[row]; if (v < 0) v = 0;
        asrc[q] = act + (size_t)v * I_DIM + lc * 8;
        ad[q] = i * 8;
    }
    const int brow = tid >> 1;
    const int bc32 = (tid & 1) * 32;
    const float* bsrc = w2 + ((size_t)e * H_DIM + tn * 128 + brow) * I_DIM + bc32;
    const int lcb = (tid & 1) * 4;
    u16* bd[4];
#pragma unroll
    for (int j = 0; j < 4; ++j)
        bd[j] = Bs + brow * 64 + (((lcb + j) ^ (brow & 7)) * 8);

    const int lane = tid & 63, wid = tid >> 6;
    const int wm = wid & 1, wn = wid >> 1;

    floatx4 acc[4][4];
    const floatx4 z4 = {0.f, 0.f, 0.f, 0.f};
#pragma unroll
    for (int mi = 0; mi < 4; ++mi)
#pragma unroll
        for (int ni = 0; ni < 4; ++ni) acc[mi][ni] = z4;

    int aoff[4][2], boff[4][2];
#pragma unroll
    for (int mi = 0; mi < 4; ++mi) {
        int m = wm * 64 + mi * 16 + (lane & 15);
#pragma unroll
        for (int kk = 0; kk < 2; ++kk)
            aoff[mi][kk] = m * 64 + (((kk * 4 + (lane >> 4)) ^ (m & 7)) * 8);
    }
#pragma unroll
    for (int ni = 0; ni < 4; ++ni) {
        int n = wn * 64 + ni * 16 + (lane & 15);
#pragma unroll
        for (int kk = 0; kk < 2; ++kk)
            boff[ni][kk] = n * 64 + (((kk * 4 + (lane >> 4)) ^ (n & 7)) * 8);
    }

#pragma unroll 1
    for (int k0 = 0; k0 < I_DIM; k0 += 64) {
#pragma unroll
        for (int q = 0; q < 4; ++q) gload16(asrc[q] + k0, As + ad[q]);
        {
            const float4* b4 = (const float4*)(bsrc + k0);
            float4 t0 = b4[0], t1 = b4[1], t2 = b4[2], t3 = b4[3];
            float4 t4 = b4[4], t5 = b4[5], t6 = b4[6], t7 = b4[7];
            *(bf16x8*)bd[0] = pack8(t0, t1);
            *(bf16x8*)bd[1] = pack8(t2, t3);
            *(bf16x8*)bd[2] = pack8(t4, t5);
            *(bf16x8*)bd[3] = pack8(t6, t7);
        }
        __syncthreads();
#pragma unroll
        for (int kk = 0; kk < 2; ++kk) {
            short8 a[4], b[4];
#pragma unroll
            for (int mi = 0; mi < 4; ++mi) a[mi] = *(const short8*)(As + aoff[mi][kk]);
#pragma unroll
            for (int ni = 0; ni < 4; ++ni) b[ni] = *(const short8*)(Bs + boff[ni][kk]);
#pragma unroll
            for (int mi = 0; mi < 4; ++mi)
#pragma unroll
                for (int ni = 0; ni < 4; ++ni)
                    acc[mi][ni] = mfma16(a[mi], b[ni], acc[mi][ni]);
        }
        __syncthreads();
    }

    const int hbase = tn * 128 + wn * 64;
#pragma unroll
    for (int mi = 0; mi < 4; ++mi)
#pragma unroll
        for (int ni = 0; ni < 4; ++ni)
#pragma unroll
            for (int r = 0; r < 4; ++r) {
                int row = wm * 64 + mi * 16 + (lane >> 4) * 4 + r;
                if (rowv[row] < 0) continue;
                atomicAdd(out + (size_t)rowt[row] * H_DIM + hbase + ni * 16 + (lane & 15),
                          roww[row] * acc[mi][ni][r]);
            }
}

extern "C" void kernel_launch(void* const* d_in, const int* in_sizes, int n_in,
                              void* d_out, int out_size, void* d_ws, size_t ws_size,
                              hipStream_t stream) {
    const float* x  = (const float*)d_in[0];   // [T, H]
    const float* gw = (const float*)d_in[1];   // [E, H]
    const float* w1 = (const float*)d_in[2];   // [E, 2I, H]
    const float* w2 = (const float*)d_in[3];   // [E, H, I]
    float* out = (float*)d_out;                // [T, H]

    char* ws = (char*)d_ws;
    int*   counts  = (int*)ws;                               // 256 B
    int*   entries = (int*)(ws + 256);                       // 64 KB
    float* wts     = (float*)(ws + 256 + 65536);             // 16 KB
    u16* xb  = (u16*)(ws + 131072);                  // 8 MB  (bf16 tokens)
    u16* act = xb  + (size_t)T_TOK * H_DIM;          // 11.5 MB (bf16 activations)
    u16* w1b = act + (size_t)2 * T_TOK * I_DIM;      // 92 MB bf16 w1 (pre only)
    u16* w2b = w1b + (size_t)E_NUM * I2 * H_DIM;     // 46 MB bf16 w2 (pre only)
    float* slot = (float*)w1b;   // 33.5 MB slot buffer ALIASES w1b (dead after mfma1)

    const size_t need = 131072 + 2ull * ((size_t)T_TOK * H_DIM + 2ull * T_TOK * I_DIM +
                                         (size_t)E_NUM * I2 * H_DIM +
                                         (size_t)E_NUM * H_DIM * I_DIM);
    const bool pre = (ws_size >= need);

    (void)hipMemsetAsync(counts, 0, 256, stream);

    moe_gating<<<T_TOK / 4, 256, 0, stream>>>(x, gw, xb, wts, counts, entries);

    if (pre) {
        cvt_bf16<<<4096, 256, 0, stream>>>(w1, w1b, (long)E_NUM * I2 * H_DIM / 8);
        cvt_bf16<<<4096, 256, 0, stream>>>(w2, w2b, (long)E_NUM * H_DIM * I_DIM / 8);
        moe_mfma1_pre<<<22 * 16 * E_NUM, 256, 0, stream>>>(xb, w1b, counts, entries, act);
        moe_mfma2_pre<<<16 * 16 * E_NUM, 256, 0, stream>>>(act, w2b, counts, entries, wts, slot);
        moe_combine<<<T_TOK * H_DIM / 4 / 256, 256, 0, stream>>>(slot, out);
    } else {
        (void)hipMemsetAsync(out, 0, (size_t)T_TOK * H_DIM * sizeof(float), stream);
        moe_mfma1_f32<<<22 * 16 * E_NUM, 256, 0, stream>>>(xb, w1, counts, entries, act);
        moe_mfma2_f32<<<16 * 16 * E_NUM, 256, 0, stream>>>(act, w2, counts, entries, wts, out);
    }
}